// Round 12
// baseline (141.910 us; speedup 1.0000x reference)
//
#include <hip/hip_runtime.h>

#define NN 10000    // nodes
#define NE 25000    // edges
#define DF 128      // features
#define SB 256      // block size for simple kernels
#define EPB 8       // edges per chunk (= waves per block)
#define TPB 512     // threads per emit block (8 waves)
#define NCHUNK ((NE + EPB - 1) / EPB)   // 3125 chunks
#define NPBLK 768   // persistent blocks (all co-resident: <=4 blocks/CU)

typedef float f4 __attribute__((ext_vector_type(4)));   // native vec for NT stores

// ---------------------------------------------------------------------------
// K1: new_x[e] = ((x[u]+x[v])*0.5 + ea[e])*0.5 (32 thr/edge, float4)
//     + init head[]=-1 and chunk lookback flags=0.
// ---------------------------------------------------------------------------
__global__ void k_newx_init(const float* __restrict__ x, const float* __restrict__ ea,
                            const int* __restrict__ c0, const int* __restrict__ c1,
                            float* __restrict__ out, int* __restrict__ head,
                            int* __restrict__ gFlag) {
    int tid = blockIdx.x * blockDim.x + threadIdx.x;
    if (tid < NN) head[tid] = -1;
    if (tid < NCHUNK) gFlag[tid] = 0;
    if (tid >= NE * 32) return;
    int e = tid >> 5, q = tid & 31;
    int u = c0[e], v = c1[e];
    float4 a  = ((const float4*)(x + (size_t)u * DF))[q];
    float4 bb = ((const float4*)(x + (size_t)v * DF))[q];
    float4 c  = ((const float4*)(ea + (size_t)e * DF))[q];
    float4 r;
    r.x = ((a.x + bb.x) * 0.5f + c.x) * 0.5f;
    r.y = ((a.y + bb.y) * 0.5f + c.y) * 0.5f;
    r.z = ((a.z + bb.z) * 0.5f + c.z) * 0.5f;
    r.w = ((a.w + bb.w) * 0.5f + c.w) * 0.5f;
    ((float4*)(out + (size_t)e * DF))[q] = r;
}

// ---------------------------------------------------------------------------
// K2: per-node linked lists in one pass. Separate dispatch ON PURPOSE —
// the kernel boundary is the cheap coherence point (R9/R11 lesson: any
// intra-kernel producer->consumer handoff of head/nxt loses >=10 us).
// ---------------------------------------------------------------------------
__global__ void k_link(const int* __restrict__ c0,
                       int* __restrict__ head, int* __restrict__ nxt) {
    int j = blockIdx.x * blockDim.x + threadIdx.x;
    if (j >= NE) return;
    nxt[j] = atomicExch(&head[c0[j]], j);
}

// ---------------------------------------------------------------------------
// K3: persistent-block fused emit + decoupled-lookback scan.
// Block p handles chunks p, p+NPBLK, ... ; chunk = 8 edges, one per wave.
// Each wave walks its edge's list ONCE (lane l owns element l); cnt is a
// byproduct: popc(ballot(keep)). Wave 0 scans the 8 counts + windowed-64
// lookback (status 1=aggregate, 2=inclusive; value in low 30 bits), then
// all waves emit: shfl rank-by-value for rows/cols order; attr = cnt
// identical copies of new_x[c1[i]] (2 rows / 1KB per NT store).
// Progress-safe: all NPBLK blocks co-resident and every chunk's owner is
// resident -> no dispatch-order assumption needed.
// ---------------------------------------------------------------------------
__global__ __launch_bounds__(TPB) void k_emit_scan(
        const float* __restrict__ newx,
        const int* __restrict__ c0, const int* __restrict__ c1,
        const int* __restrict__ head, const int* __restrict__ nxt,
        int* __restrict__ gFlag,
        float* __restrict__ outRows, float* __restrict__ outCols,
        float* __restrict__ outAttr) {
    __shared__ int sCnt[EPB];
    __shared__ int sExc[EPB];
    __shared__ int sBase;
    int wave = threadIdx.x >> 6, lane = threadIdx.x & 63;

    for (int ch = blockIdx.x; ch < NCHUNK; ch += NPBLK) {
        int i = ch * EPB + wave;
        int u = 0, v = 0, myj = -1, B = 0, rank = 0, cnt = 0;
        bool keep = false;

        if (i < NE) {
            u = c0[i]; v = c1[i];
            // single list walk: lane l records element l
            for (int j = head[v]; j != -1; j = nxt[j], ++B)
                if (B == lane) myj = j;
            if (B <= 64) {
                int myc1 = (myj >= 0) ? c1[myj] : -1;
                keep = (myj >= 0) && (myc1 != u);
                for (int q = 0; q < B; ++q) {
                    int jq = __shfl(myj, q);
                    int cq = __shfl(myc1, q);
                    if (cq != u && jq < myj) ++rank;
                }
                cnt = __popcll(__ballot(keep));
            } else {
                // rare fallback: strided count + reduce
                int c = 0, pos = 0;
                for (int j = head[v]; j != -1; j = nxt[j], ++pos)
                    if ((pos & 63) == lane && c1[j] != u) ++c;
                for (int off = 32; off; off >>= 1) c += __shfl_down(c, off, 64);
                cnt = __shfl(c, 0);
            }
        }
        if (lane == 0) sCnt[wave] = cnt;
        __syncthreads();

        // ---- wave 0: scan 8 counts + lookback ----
        if (wave == 0) {
            int c8 = (lane < EPB) ? sCnt[lane] : 0;
            for (int off = 1; off < EPB; off <<= 1) {
                int vv = __shfl_up(c8, off, 64);
                if (lane >= off) c8 += vv;
            }
            int agg = __shfl(c8, EPB - 1);
            if (lane < EPB) sExc[lane] = c8 - sCnt[lane];
            int base = 0;
            if (ch == 0) {
                if (lane == 0) atomicExch(&gFlag[0], (2 << 30) | agg);
            } else {
                if (lane == 0) atomicExch(&gFlag[ch], (1 << 30) | agg);
                int p = ch - 1;
                while (true) {
                    int idx = p - lane;
                    int st, sm;
                    if (idx < 0) { st = 2; sm = 0; }
                    else {
                        int f;
                        do {
                            f = __hip_atomic_load(&gFlag[idx], __ATOMIC_ACQUIRE,
                                                  __HIP_MEMORY_SCOPE_AGENT);
                            st = (unsigned)f >> 30;
                        } while (st == 0);
                        sm = f & 0x3FFFFFFF;
                    }
                    unsigned long long inclMask = __ballot(st == 2);
                    int contrib;
                    if (inclMask) {
                        int l0 = __ffsll(inclMask) - 1;   // nearest inclusive
                        contrib = (lane <= l0) ? sm : 0;
                    } else {
                        contrib = sm;
                    }
                    for (int off = 32; off; off >>= 1)
                        contrib += __shfl_down(contrib, off, 64);
                    contrib = __shfl(contrib, 0);
                    base += contrib;
                    if (inclMask) break;
                    p -= 64;
                }
                if (lane == 0) atomicExch(&gFlag[ch], (2 << 30) | (base + agg));
            }
            if (lane == 0) sBase = base;
        }
        __syncthreads();

        // ---- emit ----
        if (i < NE && cnt > 0) {
            int base = sBase + sExc[wave];
            if (B <= 64) {
                if (keep) {
                    __builtin_nontemporal_store((float)i, &outRows[base + rank]);
                    __builtin_nontemporal_store((float)myj, &outCols[base + rank]);
                }
            } else {
                int pos = 0;
                for (int j = head[v]; j != -1; j = nxt[j], ++pos) {
                    if ((pos & 63) != lane) continue;
                    if (c1[j] == u) continue;
                    int rk = 0;
                    for (int j2 = head[v]; j2 != -1; j2 = nxt[j2])
                        rk += (c1[j2] != u && j2 < j) ? 1 : 0;
                    __builtin_nontemporal_store((float)i, &outRows[base + rk]);
                    __builtin_nontemporal_store((float)j, &outCols[base + rk]);
                }
            }
            // attr: cnt identical copies of new_x[v]; 2 rows / 1KB per store
            f4 val = ((const f4*)(newx + (size_t)v * DF))[lane & 31];
            for (int tt = (lane >> 5); tt < cnt; tt += 2)
                __builtin_nontemporal_store(val,
                    &((f4*)(outAttr + (size_t)(base + tt) * DF))[lane & 31]);
        }
        __syncthreads();   // protect sCnt/sExc/sBase before next chunk
    }
}

// ---------------------------------------------------------------------------

extern "C" void kernel_launch(void* const* d_in, const int* in_sizes, int n_in,
                              void* d_out, int out_size, void* d_ws, size_t ws_size,
                              hipStream_t stream) {
    const float* x  = (const float*)d_in[0];
    const float* ea = (const float*)d_in[1];
    const int*   ei = (const int*)d_in[2];
    const int* c0 = ei;        // edge_index[0]
    const int* c1 = ei + NE;   // edge_index[1]

    float* out = (float*)d_out;
    int E_lg = (out_size - NE * DF) / (DF + 2);
    if (E_lg < 0) E_lg = 0;

    float* out_newx = out;                      // NE*DF
    float* out_rows = out + (size_t)NE * DF;    // E_lg
    float* out_cols = out_rows + E_lg;          // E_lg
    float* out_attr = out_cols + E_lg;          // E_lg*DF

    int* ws    = (int*)d_ws;
    int* head  = ws;                            // NN
    int* nxt   = head + NN;                     // NE
    int* gFlag = nxt + NE;                      // NCHUNK

    k_newx_init<<<(NE * 32 + SB - 1) / SB, SB, 0, stream>>>(x, ea, c0, c1, out_newx,
                                                            head, gFlag);
    k_link<<<(NE + SB - 1) / SB, SB, 0, stream>>>(c0, head, nxt);
    k_emit_scan<<<NPBLK, TPB, 0, stream>>>(out_newx, c0, c1, head, nxt, gFlag,
                                           out_rows, out_cols, out_attr);
}

// Round 13
// 42.315 us; speedup vs baseline: 3.3537x; 3.3537x over previous
//
#include <hip/hip_runtime.h>

#define NN 10000    // nodes
#define NE 25000    // edges
#define DF 128      // features
#define SB 256      // block size
#define NBLK ((NE + SB - 1) / SB)          // 98 cnt/scan blocks
#define NEWXB ((NE * 32 + SB - 1) / SB)    // 3125 newx-role blocks
#define EMITB ((NE * 64) / SB)             // 6250 emit-role blocks

typedef float f4 __attribute__((ext_vector_type(4)));   // native vec for NT stores

// ---------------------------------------------------------------------------
// K1: tiny init — head[]=-1, lookback flags=0. (Must be its own dispatch:
// link's atomicExch needs initialized head, and intra-dispatch block order
// is undefined.)
// ---------------------------------------------------------------------------
__global__ void k_init(int* __restrict__ head, int* __restrict__ gFlag) {
    int tid = blockIdx.x * blockDim.x + threadIdx.x;
    if (tid < NN) head[tid] = -1;
    if (tid < NBLK) gFlag[tid] = 0;
}

// ---------------------------------------------------------------------------
// K2: per-node linked lists in one pass. Kernel boundary = cheap coherence
// point (R9/R11/R12 lesson: intra-kernel producer->consumer handoff loses).
// ---------------------------------------------------------------------------
__global__ void k_link(const int* __restrict__ c0,
                       int* __restrict__ head, int* __restrict__ nxt) {
    int j = blockIdx.x * blockDim.x + threadIdx.x;
    if (j >= NE) return;
    nxt[j] = atomicExch(&head[c0[j]], j);
}

// ---------------------------------------------------------------------------
// K3: fused cnt_edge + exclusive scan (R6's proven 98-block version).
// Per-thread list-walk count, LDS inclusive scan, publish blockSum+1,
// parallel lookback (thread t spins on block t's flag), reduce -> base.
// All 98 blocks instantly co-resident -> spin-safe.
// ---------------------------------------------------------------------------
__global__ __launch_bounds__(SB) void k_cnt_scan(const int* __restrict__ c0,
                                                 const int* __restrict__ c1,
                                                 const int* __restrict__ head,
                                                 const int* __restrict__ nxt,
                                                 int* __restrict__ gFlag,
                                                 int* __restrict__ rowStart) {
    __shared__ int sc[SB];
    __shared__ int sr[SB];
    int b = blockIdx.x, t = threadIdx.x;
    int i = b * SB + t;
    int cnt = 0;
    if (i < NE) {
        int u = c0[i], v = c1[i];
        for (int j = head[v]; j != -1; j = nxt[j])
            if (c1[j] != u) ++cnt;
    }
    sc[t] = cnt;
    __syncthreads();
    for (int off = 1; off < SB; off <<= 1) {
        int add = (t >= off) ? sc[t - off] : 0;
        __syncthreads();
        sc[t] += add;
        __syncthreads();
    }
    int blockSum = sc[SB - 1];
    if (t == 0) atomicExch(&gFlag[b], blockSum + 1);   // publish
    int val = 0;
    if (t < b) {                                       // parallel lookback
        int v2;
        do { v2 = atomicAdd(&gFlag[t], 0); } while (v2 == 0);
        val = v2 - 1;
    }
    sr[t] = val;
    __syncthreads();
    for (int off = SB / 2; off > 0; off >>= 1) {
        if (t < off) sr[t] += sr[t + off];
        __syncthreads();
    }
    int base = sr[0];
    if (i < NE) rowStart[i] = base + sc[t] - cnt;      // exclusive
    if (b == NBLK - 1 && t == 0) rowStart[NE] = base + blockSum;
}

// ---------------------------------------------------------------------------
// K4: ONE dispatch, two independent block roles (no cross-block dataflow):
//  blocks [0, NEWXB):       new_x[e] = ((x[u]+x[v])*0.5 + ea[e])*0.5
//  blocks [NEWXB, +EMITB):  wave-per-edge emit. attr rows are recomputed
//      on the fly from x/ea (emit does NOT depend on new_x -> newx moved
//      off the serial chain into this dispatch).
// ---------------------------------------------------------------------------
__global__ __launch_bounds__(SB) void k_emit_newx(
        const float* __restrict__ x, const float* __restrict__ ea,
        const int* __restrict__ c0, const int* __restrict__ c1,
        const int* __restrict__ head, const int* __restrict__ nxt,
        const int* __restrict__ rowStart,
        float* __restrict__ outNewx,
        float* __restrict__ outRows, float* __restrict__ outCols,
        float* __restrict__ outAttr) {
    int b = blockIdx.x, t = threadIdx.x;

    if (b < NEWXB) {
        // ---- newx role ----
        int tid = b * SB + t;
        if (tid >= NE * 32) return;
        int e = tid >> 5, q = tid & 31;
        int u = c0[e], v = c1[e];
        float4 a  = ((const float4*)(x + (size_t)u * DF))[q];
        float4 bb = ((const float4*)(x + (size_t)v * DF))[q];
        float4 c  = ((const float4*)(ea + (size_t)e * DF))[q];
        float4 r;
        r.x = ((a.x + bb.x) * 0.5f + c.x) * 0.5f;
        r.y = ((a.y + bb.y) * 0.5f + c.y) * 0.5f;
        r.z = ((a.z + bb.z) * 0.5f + c.z) * 0.5f;
        r.w = ((a.w + bb.w) * 0.5f + c.w) * 0.5f;
        ((float4*)(outNewx + (size_t)e * DF))[q] = r;
        return;
    }

    // ---- emit role: one wave per edge i ----
    int gtid = (b - NEWXB) * SB + t;
    int i = gtid >> 6, lane = gtid & 63;
    if (i >= NE) return;
    int base = rowStart[i];
    int cnt  = rowStart[i + 1] - base;
    if (cnt == 0) return;
    int u = c0[i], v = c1[i];

    // walk list once; lane l records element l
    int myj = -1, B = 0;
    for (int j = head[v]; j != -1; j = nxt[j], ++B)
        if (B == lane) myj = j;

    if (B <= 64) {
        int myc1 = (myj >= 0) ? c1[myj] : -1;
        bool keep = (myj >= 0) && (myc1 != u);
        int rank = 0;
        for (int q = 0; q < B; ++q) {
            int jq = __shfl(myj, q);
            int cq = __shfl(myc1, q);
            if (cq != u && jq < myj) ++rank;
        }
        if (keep) {
            __builtin_nontemporal_store((float)i, &outRows[base + rank]);
            __builtin_nontemporal_store((float)myj, &outCols[base + rank]);
        }
    } else {
        int pos = 0;
        for (int j = head[v]; j != -1; j = nxt[j], ++pos) {
            if ((pos & 63) != lane) continue;
            if (c1[j] == u) continue;
            int rank = 0;
            for (int j2 = head[v]; j2 != -1; j2 = nxt[j2])
                rank += (c1[j2] != u && j2 < j) ? 1 : 0;
            __builtin_nontemporal_store((float)i, &outRows[base + rank]);
            __builtin_nontemporal_store((float)j, &outCols[base + rank]);
        }
    }

    // attr: cnt identical copies of new_x[v] RECOMPUTED from x/ea
    // (v = c1[i] < NN <= NE, so edge v exists; matches reference indexing).
    int vu = c0[v], vv = c1[v];
    f4 xa = ((const f4*)(x  + (size_t)vu * DF))[lane & 31];
    f4 xb = ((const f4*)(x  + (size_t)vv * DF))[lane & 31];
    f4 ec = ((const f4*)(ea + (size_t)v  * DF))[lane & 31];
    f4 val = ((xa + xb) * 0.5f + ec) * 0.5f;
    for (int tt = (lane >> 5); tt < cnt; tt += 2)
        __builtin_nontemporal_store(val,
            &((f4*)(outAttr + (size_t)(base + tt) * DF))[lane & 31]);
}

// ---------------------------------------------------------------------------

extern "C" void kernel_launch(void* const* d_in, const int* in_sizes, int n_in,
                              void* d_out, int out_size, void* d_ws, size_t ws_size,
                              hipStream_t stream) {
    const float* x  = (const float*)d_in[0];
    const float* ea = (const float*)d_in[1];
    const int*   ei = (const int*)d_in[2];
    const int* c0 = ei;        // edge_index[0]
    const int* c1 = ei + NE;   // edge_index[1]

    float* out = (float*)d_out;
    int E_lg = (out_size - NE * DF) / (DF + 2);
    if (E_lg < 0) E_lg = 0;

    float* out_newx = out;                      // NE*DF
    float* out_rows = out + (size_t)NE * DF;    // E_lg
    float* out_cols = out_rows + E_lg;          // E_lg
    float* out_attr = out_cols + E_lg;          // E_lg*DF

    int* ws       = (int*)d_ws;
    int* head     = ws;                         // NN
    int* nxt      = head + NN;                  // NE
    int* rowStart = nxt + NE;                   // NE+1
    int* gFlag    = rowStart + NE + 1;          // NBLK

    k_init<<<(NN + SB - 1) / SB, SB, 0, stream>>>(head, gFlag);
    k_link<<<(NE + SB - 1) / SB, SB, 0, stream>>>(c0, head, nxt);
    k_cnt_scan<<<NBLK, SB, 0, stream>>>(c0, c1, head, nxt, gFlag, rowStart);
    k_emit_newx<<<NEWXB + EMITB, SB, 0, stream>>>(x, ea, c0, c1, head, nxt, rowStart,
                                                  out_newx, out_rows, out_cols, out_attr);
}